// Round 7
// baseline (2727.864 us; speedup 1.0000x reference)
//
#include <hip/hip_runtime.h>
#include <hip/hip_bf16.h>

#define BATCH 256
#define SEQ   256
#define IND   128
#define HID   1024
#define OUTD  10

#define NCOLG 32           // 32 column groups of 32 cols (R4/R6-proven topology)
#define NROWG 8            // 8 row groups of 32 rows
#define ROWG_ELEMS (HID*32)     // one rowg h-tile: 32768 bf16 = 64 KB
#define CTR_OFF (2*BATCH*HID)   // flags after the two H buffers (same as R2/R4/R6)

typedef __bf16 bf16x8 __attribute__((ext_vector_type(8)));
typedef float  f32x16 __attribute__((ext_vector_type(16)));
typedef unsigned long long u64;

union Pack4 { u64 q; __bf16 h[4]; };

__device__ __forceinline__ float fast_tanh(float z) {
    float e = __expf(-2.0f * fabsf(z));
    float t = (1.0f - e) / (1.0f + e);
    return copysignf(t, z);
}

__global__ __launch_bounds__(256, 1)
void rnn_persistent(const float* __restrict__ x,
                    const float* __restrict__ Whx,
                    const float* __restrict__ Whh,
                    const float* __restrict__ bh,
                    const float* __restrict__ Why,
                    const float* __restrict__ bo,
                    float* __restrict__ out,
                    __bf16* __restrict__ ws)
{
    const int tid  = threadIdx.x;
    const int lane = tid & 63;
    const int wave = tid >> 6;
    const int bx   = blockIdx.x;
    const int colg = bx & (NCOLG-1);
    const int rowg = bx >> 5;
    const int c0 = colg * 32;
    const int r0 = rowg * 32;
    const int ln31  = lane & 31;
    const int lhalf = lane >> 5;

    __bf16* hb = ws;
    // Per-WG flags: BIT-IDENTICAL to passing R4/R6.
    int* flags  = (int*)(ws + CTR_OFF);
    int* myflag = flags + rowg*32 + colg;
    int* pollp  = flags + rowg*32 + ln31;

    __shared__ float red[4][32][32];   // 16 KB: cross-wave K-reduction

    // ---- one-time: register-resident B fragments, hi/lo split (as R6) ----
    // B-frag layout (32x32x16): n = lane&31, k = (lane>>5)*8 + j
    bf16x8 whh_hi[16], whh_lo[16];
    {
        const int nn = c0 + ln31;
        #pragma unroll
        for (int kk = 0; kk < 16; ++kk) {
            const int kb = wave*256 + kk*16 + lhalf*8;
            #pragma unroll
            for (int j = 0; j < 8; ++j) {
                float v = Whh[(size_t)(kb + j)*HID + nn];
                __bf16 h = (__bf16)v;
                whh_hi[kk][j] = h;
                whh_lo[kk][j] = (__bf16)(v - (float)h);
            }
        }
    }
    bf16x8 whx_hi[2], whx_lo[2];
    {
        const int nn = c0 + ln31;
        #pragma unroll
        for (int kk = 0; kk < 2; ++kk) {
            const int kb = wave*32 + kk*16 + lhalf*8;
            #pragma unroll
            for (int j = 0; j < 8; ++j) {
                float v = Whx[(size_t)(kb + j)*HID + nn];
                __bf16 h = (__bf16)v;
                whx_hi[kk][j] = h;
                whx_lo[kk][j] = (__bf16)(v - (float)h);
            }
        }
    }
    // Store/epilogue assignment: thread -> (row = tid>>3, cols scq..scq+3)
    const int srow = tid >> 3;
    const int scq  = (tid & 7) * 4;
    const float4 bh4 = *(const float4*)(bh + c0 + scq);
    const size_t xrow_base = (size_t)(r0 + ln31) * (SEQ*IND) + wave*32 + lhalf*8;
    // K-blocked lane-contiguous h layout (R6-proven), per (buf, rowg) region:
    //   u64 index = kb*128 + ((k16>>3)*32 + m)*2 + ((k16>>2)&1)
    // A-frag reader: lane reads 16 B at byte (wave*16+kk)*1024 + lane*16.
    const int sc  = c0 + scq;                 // first of this thread's 4 cols
    const int soffq = (sc >> 4)*128 + (((sc >> 3) & 1)*32 + srow)*2 + ((sc >> 2) & 1);

    for (int t = 0; t < SEQ; ++t) {
        const int cur = t & 1;
        const int nxt = cur ^ 1;
        f32x16 acc0{}, acc1{};

        // ---- x(t) contribution: h-independent, overlaps flag/store latency.
        // 3-pass hi/lo split: AhiBhi + AhiBlo + AloBhi  (bit-identical to R6)
        {
            const float* xp = x + xrow_base + (size_t)t*IND;
            #pragma unroll
            for (int kk = 0; kk < 2; ++kk) {
                const float4* p = (const float4*)(xp + kk*16);
                float4 v0 = p[0], v1 = p[1];
                float vv[8] = {v0.x,v0.y,v0.z,v0.w,v1.x,v1.y,v1.z,v1.w};
                bf16x8 ahi, alo;
                #pragma unroll
                for (int j = 0; j < 8; ++j) {
                    __bf16 h = (__bf16)vv[j];
                    ahi[j] = h;
                    alo[j] = (__bf16)(vv[j] - (float)h);
                }
                acc0 = __builtin_amdgcn_mfma_f32_32x32x16_bf16(ahi, whx_hi[kk], acc0, 0,0,0);
                acc1 = __builtin_amdgcn_mfma_f32_32x32x16_bf16(ahi, whx_lo[kk], acc1, 0,0,0);
                acc0 = __builtin_amdgcn_mfma_f32_32x32x16_bf16(alo, whx_hi[kk], acc0, 0,0,0);
            }
        }

        // ---- wait for h(t), then h(t) @ Whh. t==0: h0 == 0, skip entirely.
        if (t > 0) {
            for (;;) {
                int v = __hip_atomic_load(pollp, __ATOMIC_RELAXED, __HIP_MEMORY_SCOPE_AGENT);
                if (__all(v >= t)) break;
            }
            // All waves' polls complete BEFORE any fence/load: closes the race
            // where one wave's post-fence L2 could be refilled stale by a
            // not-yet-synchronized wave. (No wave can touch h lines pre-barrier.)
            __syncthreads();
            // Acquire at agent scope: flash-invalidate this CU's L1 + XCD's L2
            // (clean lines only — h stores are write-through, LLC is truth).
            // After this, normal cached loads observe the producers' stores,
            // and the 4 same-rowg WGs on each XCD share one LLC->L2 fill.
            __builtin_amdgcn_fence(__ATOMIC_ACQUIRE, "agent");

            // A-frag via ONE cached 16-B load per lane per kb over a dense
            // 1 KB span (global_load_dwordx4, L2-served after first fill).
            const bf16x8* hq = (const bf16x8*)(hb + (size_t)(cur*NROWG + rowg)*ROWG_ELEMS);
            #pragma unroll
            for (int kk = 0; kk < 16; ++kk) {
                bf16x8 a = hq[(wave*16 + kk)*64 + lane];
                acc0 = __builtin_amdgcn_mfma_f32_32x32x16_bf16(a, whh_hi[kk], acc0, 0,0,0);
                acc1 = __builtin_amdgcn_mfma_f32_32x32x16_bf16(a, whh_lo[kk], acc1, 0,0,0);
            }
        }

        // ---- cross-wave K reduction through LDS
        // C/D layout (32x32): col=lane&31, row=(reg&3)+8*(reg>>2)+4*(lane>>5)
        #pragma unroll
        for (int r = 0; r < 16; ++r) {
            const int row = (r & 3) + 8*(r >> 2) + 4*lhalf;
            red[wave][row][ln31] = acc0[r] + acc1[r];
        }
        __syncthreads();
        {
            // thread -> (srow, cols scq..scq+3): float4 LDS reads, one 8B
            // write-through (sc0 sc1) store into the K-blocked buffer.
            const float4 s0 = *(const float4*)&red[0][srow][scq];
            const float4 s1 = *(const float4*)&red[1][srow][scq];
            const float4 s2 = *(const float4*)&red[2][srow][scq];
            const float4 s3 = *(const float4*)&red[3][srow][scq];
            float z0 = s0.x + s1.x + s2.x + s3.x + bh4.x;
            float z1 = s0.y + s1.y + s2.y + s3.y + bh4.y;
            float z2 = s0.z + s1.z + s2.z + s3.z + bh4.z;
            float z3 = s0.w + s1.w + s2.w + s3.w + bh4.w;
            Pack4 pk;
            pk.h[0] = (__bf16)fast_tanh(z0);
            pk.h[1] = (__bf16)fast_tanh(z1);
            pk.h[2] = (__bf16)fast_tanh(z2);
            pk.h[3] = (__bf16)fast_tanh(z3);
            u64* hnq = (u64*)(hb + (size_t)(nxt*NROWG + rowg)*ROWG_ELEMS) + soffq;
            __hip_atomic_store(hnq, pk.q, __ATOMIC_RELAXED, __HIP_MEMORY_SCOPE_AGENT);
        }
        // __syncthreads drains vmcnt(0) per wave => every wave's sc1 store
        // reached the coherence point before tid0 publishes the arrival.
        __syncthreads();
        if (tid == 0) {
            __hip_atomic_store(myflag, t + 1, __ATOMIC_RELAXED, __HIP_MEMORY_SCOPE_AGENT);
        }
    }

    // ---- epilogue: colg==0 WG of each row-group computes o + softmax
    if (colg == 0) {
        for (;;) {
            int v = __hip_atomic_load(pollp, __ATOMIC_RELAXED, __HIP_MEMORY_SCOPE_AGENT);
            if (__all(v >= SEQ)) break;
        }
        __syncthreads();
        // after t=255, final h is in buffer 0 (K-blocked lane-contiguous layout);
        // read with agent-scope (LLC) loads — bypasses any stale cache.
        const u64* hq0 = (const u64*)(hb + (size_t)(0*NROWG + rowg)*ROWG_ELEMS);
        float* obuf = &red[0][0][0];    // reuse LDS, 320 floats
        for (int idx = tid; idx < 32*OUTD; idx += 256) {
            const int row = idx / OUTD;      // m within rowg
            const int c   = idx - row*OUTD;
            float s = bo[c];
            #pragma unroll 8
            for (int k4 = 0; k4 < HID/4; ++k4) {
                const int k = k4*4;
                Pack4 p;
                p.q = __hip_atomic_load(hq0 + (k>>4)*128 + (((k>>3)&1)*32 + row)*2 + ((k>>2)&1),
                                        __ATOMIC_RELAXED, __HIP_MEMORY_SCOPE_AGENT);
                const float* wr = Why + (size_t)k*OUTD + c;
                s += (float)p.h[0]*wr[0] + (float)p.h[1]*wr[OUTD]
                   + (float)p.h[2]*wr[2*OUTD] + (float)p.h[3]*wr[3*OUTD];
            }
            obuf[idx] = s;
        }
        __syncthreads();
        if (tid < 32) {
            float m = -1e30f;
            #pragma unroll
            for (int c = 0; c < OUTD; ++c) m = fmaxf(m, obuf[tid*OUTD+c]);
            float e[OUTD]; float ssum = 0.f;
            #pragma unroll
            for (int c = 0; c < OUTD; ++c) { e[c] = __expf(obuf[tid*OUTD+c] - m); ssum += e[c]; }
            const float inv = 1.0f / ssum;
            #pragma unroll
            for (int c = 0; c < OUTD; ++c) out[(size_t)(r0+tid)*OUTD + c] = e[c]*inv;
        }
    }
}

extern "C" void kernel_launch(void* const* d_in, const int* in_sizes, int n_in,
                              void* d_out, int out_size, void* d_ws, size_t ws_size,
                              hipStream_t stream)
{
    const float* x   = (const float*)d_in[0];
    const float* Whx = (const float*)d_in[1];
    const float* Whh = (const float*)d_in[2];
    const float* bh  = (const float*)d_in[3];
    const float* Why = (const float*)d_in[4];
    const float* bo  = (const float*)d_in[5];
    float* out = (float*)d_out;
    __bf16* ws = (__bf16*)d_ws;

    // Zero the flag region: SAME offset and SAME 2 KB extent as passing R4/R6.
    hipMemsetAsync((char*)d_ws + (size_t)CTR_OFF*sizeof(__bf16), 0,
                   (size_t)NROWG*64*sizeof(int), stream);

    void* args[] = { &x, &Whx, &Whh, &bh, &Why, &bo, &out, &ws };
    hipLaunchCooperativeKernel((const void*)rnn_persistent,
                               dim3(NROWG*NCOLG), dim3(256), args, 0, stream);
}

// Round 8
// 1267.935 us; speedup vs baseline: 2.1514x; 2.1514x over previous
//
#include <hip/hip_runtime.h>
#include <hip/hip_bf16.h>

#define BATCH 256
#define SEQ   256
#define IND   128
#define HID   1024
#define OUTD  10

#define NCOLG 32           // 32 column groups of 32 cols (R6-proven topology)
#define NROWG 8            // 8 row groups of 32 rows
#define ROWG_ELEMS (HID*32)     // one rowg h-tile: 32768 bf16 = 64 KB
#define CTR_OFF (2*BATCH*HID)   // flags after the two H buffers (same extent as R4/R6)

typedef __bf16 bf16x8 __attribute__((ext_vector_type(8)));
typedef float  f32x16 __attribute__((ext_vector_type(16)));
typedef unsigned long long u64;

union Pack4 { u64 q; __bf16 h[4]; };
union Pack8 { u64 q[2]; bf16x8 v; };

__device__ __forceinline__ float fast_tanh(float z) {
    float e = __expf(-2.0f * fabsf(z));
    float t = (1.0f - e) / (1.0f + e);
    return copysignf(t, z);
}

__global__ __launch_bounds__(256, 1)
void rnn_persistent(const float* __restrict__ x,
                    const float* __restrict__ Whx,
                    const float* __restrict__ Whh,
                    const float* __restrict__ bh,
                    const float* __restrict__ Why,
                    const float* __restrict__ bo,
                    float* __restrict__ out,
                    __bf16* __restrict__ ws)
{
    const int tid  = threadIdx.x;
    const int lane = tid & 63;
    const int wave = tid >> 6;
    const int bx   = blockIdx.x;
    const int colg = bx & (NCOLG-1);
    const int rowg = bx >> 5;
    const int c0 = colg * 32;
    const int r0 = rowg * 32;
    const int ln31  = lane & 31;
    const int lhalf = lane >> 5;

    __bf16* hb = ws;
    // Flags: 8 rowg x 4 octets x 16 ints (64-B line per octet), 2 KB total —
    // same offset/extent as the R4/R6-proven region. Producer (rowg,colg)
    // owns int [rowg][colg>>3][colg&7]; consumer wave w needs only octet w
    // (wave w consumes k in [256w,256w+256) = cols of colgs 8w..8w+7).
    int* flags  = (int*)(ws + CTR_OFF);
    int* myflag = flags + rowg*64 + (colg >> 3)*16 + (colg & 7);
    int* pollp  = flags + rowg*64 + wave*16 + (lane & 7);

    __shared__ float red[4][32][32];   // 16 KB: cross-wave K-reduction

    // ---- one-time: register-resident B fragments, hi/lo split (as R6) ----
    // B-frag layout (32x32x16): n = lane&31, k = (lane>>5)*8 + j
    bf16x8 whh_hi[16], whh_lo[16];
    {
        const int nn = c0 + ln31;
        #pragma unroll
        for (int kk = 0; kk < 16; ++kk) {
            const int kb = wave*256 + kk*16 + lhalf*8;
            #pragma unroll
            for (int j = 0; j < 8; ++j) {
                float v = Whh[(size_t)(kb + j)*HID + nn];
                __bf16 h = (__bf16)v;
                whh_hi[kk][j] = h;
                whh_lo[kk][j] = (__bf16)(v - (float)h);
            }
        }
    }
    bf16x8 whx_hi[2], whx_lo[2];
    {
        const int nn = c0 + ln31;
        #pragma unroll
        for (int kk = 0; kk < 2; ++kk) {
            const int kb = wave*32 + kk*16 + lhalf*8;
            #pragma unroll
            for (int j = 0; j < 8; ++j) {
                float v = Whx[(size_t)(kb + j)*HID + nn];
                __bf16 h = (__bf16)v;
                whx_hi[kk][j] = h;
                whx_lo[kk][j] = (__bf16)(v - (float)h);
            }
        }
    }
    // Store/epilogue assignment: thread -> (row = tid>>3, cols scq..scq+3)
    const int srow = tid >> 3;
    const int scq  = (tid & 7) * 4;
    const float4 bh4 = *(const float4*)(bh + c0 + scq);
    const size_t xrow_base = (size_t)(r0 + ln31) * (SEQ*IND) + wave*32 + lhalf*8;
    // K-blocked lane-contiguous h layout (R6-proven), per (buf, rowg) region:
    //   u64 index = kb*128 + ((k16>>3)*32 + m)*2 + ((k16>>2)&1)
    const int sc  = c0 + scq;                 // first of this thread's 4 cols
    const int soffq = (sc >> 4)*128 + (((sc >> 3) & 1)*32 + srow)*2 + ((sc >> 2) & 1);

    for (int t = 0; t < SEQ; ++t) {
        const int cur = t & 1;
        const int nxt = cur ^ 1;
        f32x16 acc0{}, acc1{};

        // ---- x(t) contribution: h-independent, overlaps flag/store latency.
        // 3-pass hi/lo split: AhiBhi + AhiBlo + AloBhi  (bit-identical to R6)
        {
            const float* xp = x + xrow_base + (size_t)t*IND;
            #pragma unroll
            for (int kk = 0; kk < 2; ++kk) {
                const float4* p = (const float4*)(xp + kk*16);
                float4 v0 = p[0], v1 = p[1];
                float vv[8] = {v0.x,v0.y,v0.z,v0.w,v1.x,v1.y,v1.z,v1.w};
                bf16x8 ahi, alo;
                #pragma unroll
                for (int j = 0; j < 8; ++j) {
                    __bf16 h = (__bf16)vv[j];
                    ahi[j] = h;
                    alo[j] = (__bf16)(vv[j] - (float)h);
                }
                acc0 = __builtin_amdgcn_mfma_f32_32x32x16_bf16(ahi, whx_hi[kk], acc0, 0,0,0);
                acc1 = __builtin_amdgcn_mfma_f32_32x32x16_bf16(ahi, whx_lo[kk], acc1, 0,0,0);
                acc0 = __builtin_amdgcn_mfma_f32_32x32x16_bf16(alo, whx_hi[kk], acc0, 0,0,0);
            }
        }

        // ---- per-wave wait for THIS wave's 8 producers, then its K-slice of
        // h(t) @ Whh. No pre-load barrier: in-order vmem issue after the
        // successful poll load guarantees the producers' write-through stores
        // are visible at the LLC that serves the (uncached) A-frag loads.
        // t==0: h0 == 0, skip entirely.
        if (t > 0) {
            for (;;) {
                int v = __hip_atomic_load(pollp, __ATOMIC_RELAXED, __HIP_MEMORY_SCOPE_AGENT);
                if (__all(v >= t)) break;
            }
            asm volatile("" ::: "memory");   // no compiler hoist of h loads

            // A-frag from K-blocked lane-contiguous buffer: two 8B uncached
            // loads per lane per kb over a dense 1 KB span (R6-proven path).
            const u64* hq = (const u64*)(hb + (size_t)(cur*NROWG + rowg)*ROWG_ELEMS);
            #pragma unroll
            for (int kk = 0; kk < 16; ++kk) {
                const int idx = (wave*16 + kk)*128 + lane*2;
                Pack8 p;
                p.q[0] = __hip_atomic_load(hq + idx,     __ATOMIC_RELAXED, __HIP_MEMORY_SCOPE_AGENT);
                p.q[1] = __hip_atomic_load(hq + idx + 1, __ATOMIC_RELAXED, __HIP_MEMORY_SCOPE_AGENT);
                acc0 = __builtin_amdgcn_mfma_f32_32x32x16_bf16(p.v, whh_hi[kk], acc0, 0,0,0);
                acc1 = __builtin_amdgcn_mfma_f32_32x32x16_bf16(p.v, whh_lo[kk], acc1, 0,0,0);
            }
        }

        // ---- cross-wave K reduction through LDS
        // C/D layout (32x32): col=lane&31, row=(reg&3)+8*(reg>>2)+4*(lane>>5)
        #pragma unroll
        for (int r = 0; r < 16; ++r) {
            const int row = (r & 3) + 8*(r >> 2) + 4*lhalf;
            red[wave][row][ln31] = acc0[r] + acc1[r];
        }
        __syncthreads();
        {
            // thread -> (srow, cols scq..scq+3): float4 LDS reads, one 8B
            // write-through store into the K-blocked buffer.
            const float4 s0 = *(const float4*)&red[0][srow][scq];
            const float4 s1 = *(const float4*)&red[1][srow][scq];
            const float4 s2 = *(const float4*)&red[2][srow][scq];
            const float4 s3 = *(const float4*)&red[3][srow][scq];
            float z0 = s0.x + s1.x + s2.x + s3.x + bh4.x;
            float z1 = s0.y + s1.y + s2.y + s3.y + bh4.y;
            float z2 = s0.z + s1.z + s2.z + s3.z + bh4.z;
            float z3 = s0.w + s1.w + s2.w + s3.w + bh4.w;
            Pack4 pk;
            pk.h[0] = (__bf16)fast_tanh(z0);
            pk.h[1] = (__bf16)fast_tanh(z1);
            pk.h[2] = (__bf16)fast_tanh(z2);
            pk.h[3] = (__bf16)fast_tanh(z3);
            u64* hnq = (u64*)(hb + (size_t)(nxt*NROWG + rowg)*ROWG_ELEMS) + soffq;
            __hip_atomic_store(hnq, pk.q, __ATOMIC_RELAXED, __HIP_MEMORY_SCOPE_AGENT);
        }
        // __syncthreads drains vmcnt(0) per wave => every wave's sc1 store
        // reached the coherence point before tid0 publishes the arrival.
        __syncthreads();
        if (tid == 0) {
            __hip_atomic_store(myflag, t + 1, __ATOMIC_RELAXED, __HIP_MEMORY_SCOPE_AGENT);
        }
    }

    // ---- epilogue: colg==0 WG of each row-group computes o + softmax
    if (colg == 0) {
        // Need ALL 32 producers of this rowg: lanes 0..31 cover 4 octets x 8.
        int* epip = flags + rowg*64 + ((lane >> 3) & 3)*16 + (lane & 7);
        for (;;) {
            int v = __hip_atomic_load(epip, __ATOMIC_RELAXED, __HIP_MEMORY_SCOPE_AGENT);
            if (__all(v >= SEQ)) break;
        }
        asm volatile("" ::: "memory");
        __syncthreads();
        // after t=255, final h is in buffer 0 (K-blocked lane-contiguous layout)
        const u64* hq0 = (const u64*)(hb + (size_t)(0*NROWG + rowg)*ROWG_ELEMS);
        float* obuf = &red[0][0][0];    // reuse LDS, 320 floats
        for (int idx = tid; idx < 32*OUTD; idx += 256) {
            const int row = idx / OUTD;      // m within rowg
            const int c   = idx - row*OUTD;
            float s = bo[c];
            #pragma unroll 8
            for (int k4 = 0; k4 < HID/4; ++k4) {
                const int k = k4*4;
                Pack4 p;
                p.q = __hip_atomic_load(hq0 + (k>>4)*128 + (((k>>3)&1)*32 + row)*2 + ((k>>2)&1),
                                        __ATOMIC_RELAXED, __HIP_MEMORY_SCOPE_AGENT);
                const float* wr = Why + (size_t)k*OUTD + c;
                s += (float)p.h[0]*wr[0] + (float)p.h[1]*wr[OUTD]
                   + (float)p.h[2]*wr[2*OUTD] + (float)p.h[3]*wr[3*OUTD];
            }
            obuf[idx] = s;
        }
        __syncthreads();
        if (tid < 32) {
            float m = -1e30f;
            #pragma unroll
            for (int c = 0; c < OUTD; ++c) m = fmaxf(m, obuf[tid*OUTD+c]);
            float e[OUTD]; float ssum = 0.f;
            #pragma unroll
            for (int c = 0; c < OUTD; ++c) { e[c] = __expf(obuf[tid*OUTD+c] - m); ssum += e[c]; }
            const float inv = 1.0f / ssum;
            #pragma unroll
            for (int c = 0; c < OUTD; ++c) out[(size_t)(r0+tid)*OUTD + c] = e[c]*inv;
        }
    }
}

extern "C" void kernel_launch(void* const* d_in, const int* in_sizes, int n_in,
                              void* d_out, int out_size, void* d_ws, size_t ws_size,
                              hipStream_t stream)
{
    const float* x   = (const float*)d_in[0];
    const float* Whx = (const float*)d_in[1];
    const float* Whh = (const float*)d_in[2];
    const float* bh  = (const float*)d_in[3];
    const float* Why = (const float*)d_in[4];
    const float* bo  = (const float*)d_in[5];
    float* out = (float*)d_out;
    __bf16* ws = (__bf16*)d_ws;

    // Zero the flag region: SAME offset and SAME 2 KB extent as passing R4/R6.
    hipMemsetAsync((char*)d_ws + (size_t)CTR_OFF*sizeof(__bf16), 0,
                   (size_t)NROWG*64*sizeof(int), stream);

    void* args[] = { &x, &Whx, &Whh, &bh, &Why, &bo, &out, &ws };
    hipLaunchCooperativeKernel((const void*)rnn_persistent,
                               dim3(NROWG*NCOLG), dim3(256), args, 0, stream);
}

// Round 10
// 1139.449 us; speedup vs baseline: 2.3940x; 1.1128x over previous
//
#include <hip/hip_runtime.h>
#include <hip/hip_bf16.h>

#define BATCH 256
#define SEQ   256
#define IND   128
#define HID   1024
#define OUTD  10

#define NCOLG 32           // 32 column groups of 32 cols (R6/R8-proven topology)
#define NROWG 8            // 8 row groups of 32 rows
#define ROWG_ELEMS (HID*32)     // one rowg h-tile: 32768 bf16 = 64 KB
#define CTR_OFF (2*BATCH*HID)   // flags after the two H buffers (same extent as R4/R6/R8)

typedef __bf16 bf16x8 __attribute__((ext_vector_type(8)));
typedef float  f32x16 __attribute__((ext_vector_type(16)));
typedef unsigned long long u64;

union Pack4 { u64 q; __bf16 h[4]; };
union Pack8 { u64 q[2]; bf16x8 v; };

__device__ __forceinline__ float fast_tanh(float z) {
    float e = __expf(-2.0f * fabsf(z));
    float t = (1.0f - e) / (1.0f + e);
    return copysignf(t, z);
}

__global__ __launch_bounds__(256, 1)
void rnn_persistent(const float* __restrict__ x,
                    const float* __restrict__ Whx,
                    const float* __restrict__ Whh,
                    const float* __restrict__ bh,
                    const float* __restrict__ Why,
                    const float* __restrict__ bo,
                    float* __restrict__ out,
                    __bf16* __restrict__ ws)
{
    const int tid  = threadIdx.x;
    const int lane = tid & 63;
    const int wave = tid >> 6;
    const int bx   = blockIdx.x;
    const int colg = bx & (NCOLG-1);
    const int rowg = bx >> 5;
    const int c0 = colg * 32;
    const int r0 = rowg * 32;
    const int ln31  = lane & 31;
    const int lhalf = lane >> 5;

    __bf16* hb = ws;
    // Flags: 8 rowg x 4 octets x 16 ints (64-B line per octet) — R8-proven.
    int* flags  = (int*)(ws + CTR_OFF);
    int* myflag = flags + rowg*64 + (colg >> 3)*16 + (colg & 7);
    int* pollp  = flags + rowg*64 + wave*16 + (lane & 7);

    __shared__ float red[4][32][32];   // 16 KB: cross-wave K-reduction

    // ---- one-time: register-resident B fragments, hi/lo split (as R6/R8) ----
    // B-frag layout (32x32x16): n = lane&31, k = (lane>>5)*8 + j
    bf16x8 whh_hi[16], whh_lo[16];
    {
        const int nn = c0 + ln31;
        #pragma unroll
        for (int kk = 0; kk < 16; ++kk) {
            const int kb = wave*256 + kk*16 + lhalf*8;
            #pragma unroll
            for (int j = 0; j < 8; ++j) {
                float v = Whh[(size_t)(kb + j)*HID + nn];
                __bf16 h = (__bf16)v;
                whh_hi[kk][j] = h;
                whh_lo[kk][j] = (__bf16)(v - (float)h);
            }
        }
    }
    bf16x8 whx_hi[2], whx_lo[2];
    {
        const int nn = c0 + ln31;
        #pragma unroll
        for (int kk = 0; kk < 2; ++kk) {
            const int kb = wave*32 + kk*16 + lhalf*8;
            #pragma unroll
            for (int j = 0; j < 8; ++j) {
                float v = Whx[(size_t)(kb + j)*HID + nn];
                __bf16 h = (__bf16)v;
                whx_hi[kk][j] = h;
                whx_lo[kk][j] = (__bf16)(v - (float)h);
            }
        }
    }
    // Store/epilogue assignment: thread -> (row = tid>>3, cols scq..scq+3)
    const int srow = tid >> 3;
    const int scq  = (tid & 7) * 4;
    const float4 bh4 = *(const float4*)(bh + c0 + scq);
    const size_t xrow_base = (size_t)(r0 + ln31) * (SEQ*IND) + wave*32 + lhalf*8;
    // K-blocked lane-contiguous h layout (R6-proven), per (buf, rowg) region:
    //   u64 index = kb*128 + ((k16>>3)*32 + m)*2 + ((k16>>2)&1)
    const int sc  = c0 + scq;                 // first of this thread's 4 cols
    const int soffq = (sc >> 4)*128 + (((sc >> 3) & 1)*32 + srow)*2 + ((sc >> 2) & 1);

    for (int t = 0; t < SEQ; ++t) {
        const int cur = t & 1;
        const int nxt = cur ^ 1;
        f32x16 acc0{}, acc1{};

        // ---- x(t) contribution: h-independent, overlaps flag/store latency.
        // 3-pass hi/lo split: AhiBhi + AhiBlo + AloBhi  (bit-identical to R8)
        {
            const float* xp = x + xrow_base + (size_t)t*IND;
            #pragma unroll
            for (int kk = 0; kk < 2; ++kk) {
                const float4* p = (const float4*)(xp + kk*16);
                float4 v0 = p[0], v1 = p[1];
                float vv[8] = {v0.x,v0.y,v0.z,v0.w,v1.x,v1.y,v1.z,v1.w};
                bf16x8 ahi, alo;
                #pragma unroll
                for (int j = 0; j < 8; ++j) {
                    __bf16 h = (__bf16)vv[j];
                    ahi[j] = h;
                    alo[j] = (__bf16)(vv[j] - (float)h);
                }
                acc0 = __builtin_amdgcn_mfma_f32_32x32x16_bf16(ahi, whx_hi[kk], acc0, 0,0,0);
                acc1 = __builtin_amdgcn_mfma_f32_32x32x16_bf16(ahi, whx_lo[kk], acc1, 0,0,0);
                acc0 = __builtin_amdgcn_mfma_f32_32x32x16_bf16(alo, whx_hi[kk], acc0, 0,0,0);
            }
        }

        // ---- per-wave wait for THIS wave's 8 producers, then its K-slice of
        // h(t) @ Whh. t==0: h0 == 0, skip entirely.
        if (t > 0) {
            for (;;) {
                int v = __hip_atomic_load(pollp, __ATOMIC_RELAXED, __HIP_MEMORY_SCOPE_AGENT);
                if (__all(v >= t)) break;
            }
            asm volatile("" ::: "memory");   // no compiler hoist of h loads

            // A-frags: stage ALL 32 uncached 8B loads into registers first
            // (one latency exposure), THEN run the 32 MFMAs. R8 interleaved
            // load->mfma, leaving only a few loads in flight at 1 wave/SIMD.
            const u64* hq = (const u64*)(hb + (size_t)(cur*NROWG + rowg)*ROWG_ELEMS);
            Pack8 pa[16];
            #pragma unroll
            for (int kk = 0; kk < 16; ++kk) {
                const int idx = (wave*16 + kk)*128 + lane*2;
                pa[kk].q[0] = __hip_atomic_load(hq + idx,     __ATOMIC_RELAXED, __HIP_MEMORY_SCOPE_AGENT);
                pa[kk].q[1] = __hip_atomic_load(hq + idx + 1, __ATOMIC_RELAXED, __HIP_MEMORY_SCOPE_AGENT);
            }
            // Pin schedule: all 32 VMEM reads issue before the MFMA block.
            __builtin_amdgcn_sched_group_barrier(0x020, 32, 0);  // 32 VMEM reads
            __builtin_amdgcn_sched_group_barrier(0x008, 32, 0);  // 32 MFMAs
            #pragma unroll
            for (int kk = 0; kk < 16; ++kk) {
                acc0 = __builtin_amdgcn_mfma_f32_32x32x16_bf16(pa[kk].v, whh_hi[kk], acc0, 0,0,0);
                acc1 = __builtin_amdgcn_mfma_f32_32x32x16_bf16(pa[kk].v, whh_lo[kk], acc1, 0,0,0);
            }
        }

        // ---- cross-wave K reduction through LDS
        // C/D layout (32x32): col=lane&31, row=(reg&3)+8*(reg>>2)+4*(lane>>5)
        #pragma unroll
        for (int r = 0; r < 16; ++r) {
            const int row = (r & 3) + 8*(r >> 2) + 4*lhalf;
            red[wave][row][ln31] = acc0[r] + acc1[r];
        }
        __syncthreads();
        {
            // thread -> (srow, cols scq..scq+3): float4 LDS reads, one 8B
            // write-through store into the K-blocked buffer.
            const float4 s0 = *(const float4*)&red[0][srow][scq];
            const float4 s1 = *(const float4*)&red[1][srow][scq];
            const float4 s2 = *(const float4*)&red[2][srow][scq];
            const float4 s3 = *(const float4*)&red[3][srow][scq];
            float z0 = s0.x + s1.x + s2.x + s3.x + bh4.x;
            float z1 = s0.y + s1.y + s2.y + s3.y + bh4.y;
            float z2 = s0.z + s1.z + s2.z + s3.z + bh4.z;
            float z3 = s0.w + s1.w + s2.w + s3.w + bh4.w;
            Pack4 pk;
            pk.h[0] = (__bf16)fast_tanh(z0);
            pk.h[1] = (__bf16)fast_tanh(z1);
            pk.h[2] = (__bf16)fast_tanh(z2);
            pk.h[3] = (__bf16)fast_tanh(z3);
            u64* hnq = (u64*)(hb + (size_t)(nxt*NROWG + rowg)*ROWG_ELEMS) + soffq;
            __hip_atomic_store(hnq, pk.q, __ATOMIC_RELAXED, __HIP_MEMORY_SCOPE_AGENT);
        }
        // __syncthreads drains vmcnt(0) per wave => every wave's sc1 store
        // reached the coherence point before tid0 publishes the arrival.
        __syncthreads();
        if (tid == 0) {
            __hip_atomic_store(myflag, t + 1, __ATOMIC_RELAXED, __HIP_MEMORY_SCOPE_AGENT);
        }
    }

    // ---- epilogue: colg==0 WG of each row-group computes o + softmax
    if (colg == 0) {
        // Need ALL 32 producers of this rowg: lanes 0..31 cover 4 octets x 8.
        int* epip = flags + rowg*64 + ((lane >> 3) & 3)*16 + (lane & 7);
        for (;;) {
            int v = __hip_atomic_load(epip, __ATOMIC_RELAXED, __HIP_MEMORY_SCOPE_AGENT);
            if (__all(v >= SEQ)) break;
        }
        asm volatile("" ::: "memory");
        __syncthreads();
        // after t=255, final h is in buffer 0 (K-blocked lane-contiguous layout)
        const u64* hq0 = (const u64*)(hb + (size_t)(0*NROWG + rowg)*ROWG_ELEMS);
        float* obuf = &red[0][0][0];    // reuse LDS, 320 floats
        for (int idx = tid; idx < 32*OUTD; idx += 256) {
            const int row = idx / OUTD;      // m within rowg
            const int c   = idx - row*OUTD;
            float s = bo[c];
            #pragma unroll 8
            for (int k4 = 0; k4 < HID/4; ++k4) {
                const int k = k4*4;
                Pack4 p;
                p.q = __hip_atomic_load(hq0 + (k>>4)*128 + (((k>>3)&1)*32 + row)*2 + ((k>>2)&1),
                                        __ATOMIC_RELAXED, __HIP_MEMORY_SCOPE_AGENT);
                const float* wr = Why + (size_t)k*OUTD + c;
                s += (float)p.h[0]*wr[0] + (float)p.h[1]*wr[OUTD]
                   + (float)p.h[2]*wr[2*OUTD] + (float)p.h[3]*wr[3*OUTD];
            }
            obuf[idx] = s;
        }
        __syncthreads();
        if (tid < 32) {
            float m = -1e30f;
            #pragma unroll
            for (int c = 0; c < OUTD; ++c) m = fmaxf(m, obuf[tid*OUTD+c]);
            float e[OUTD]; float ssum = 0.f;
            #pragma unroll
            for (int c = 0; c < OUTD; ++c) { e[c] = __expf(obuf[tid*OUTD+c] - m); ssum += e[c]; }
            const float inv = 1.0f / ssum;
            #pragma unroll
            for (int c = 0; c < OUTD; ++c) out[(size_t)(r0+tid)*OUTD + c] = e[c]*inv;
        }
    }
}

extern "C" void kernel_launch(void* const* d_in, const int* in_sizes, int n_in,
                              void* d_out, int out_size, void* d_ws, size_t ws_size,
                              hipStream_t stream)
{
    const float* x   = (const float*)d_in[0];
    const float* Whx = (const float*)d_in[1];
    const float* Whh = (const float*)d_in[2];
    const float* bh  = (const float*)d_in[3];
    const float* Why = (const float*)d_in[4];
    const float* bo  = (const float*)d_in[5];
    float* out = (float*)d_out;
    __bf16* ws = (__bf16*)d_ws;

    // Zero the flag region: SAME offset and SAME 2 KB extent as passing R4/R6/R8.
    hipMemsetAsync((char*)d_ws + (size_t)CTR_OFF*sizeof(__bf16), 0,
                   (size_t)NROWG*64*sizeof(int), stream);

    void* args[] = { &x, &Whx, &Whh, &bh, &Why, &bo, &out, &ws };
    hipLaunchCooperativeKernel((const void*)rnn_persistent,
                               dim3(NROWG*NCOLG), dim3(256), args, 0, stream);
}

// Round 12
// 1137.036 us; speedup vs baseline: 2.3991x; 1.0021x over previous
//
#include <hip/hip_runtime.h>
#include <hip/hip_bf16.h>

#define BATCH 256
#define SEQ   256
#define IND   128
#define HID   1024
#define OUTD  10

#define NCOLG 32           // 32 column groups of 32 cols (proven topology)
#define NROWG 8            // 8 row groups of 32 rows
#define ROWG_ELEMS (HID*32)     // one rowg h-tile: 32768 bf16 = 64 KB
#define CTR_OFF (2*BATCH*HID)   // flags after the two H buffers (proven extent)

typedef __bf16 bf16x8 __attribute__((ext_vector_type(8)));
typedef float  f32x16 __attribute__((ext_vector_type(16)));
typedef unsigned long long u64;

union Pack4 { u64 q; __bf16 h[4]; };
union Pack8 { u64 q[2]; bf16x8 v; };

__device__ __forceinline__ float fast_tanh(float z) {
    float e = __expf(-2.0f * fabsf(z));
    float t = (1.0f - e) / (1.0f + e);
    return copysignf(t, z);
}

__global__ __launch_bounds__(256, 1)
void rnn_persistent(const float* __restrict__ x,
                    const float* __restrict__ Whx,
                    const float* __restrict__ Whh,
                    const float* __restrict__ bh,
                    const float* __restrict__ Why,
                    const float* __restrict__ bo,
                    float* __restrict__ out,
                    __bf16* __restrict__ ws)
{
    const int tid  = threadIdx.x;
    const int lane = tid & 63;
    const int wave = tid >> 6;
    const int bx   = blockIdx.x;
    const int colg = bx & (NCOLG-1);
    const int rowg = bx >> 5;
    const int c0 = colg * 32;
    const int r0 = rowg * 32;
    const int ln31  = lane & 31;
    const int lhalf = lane >> 5;

    __bf16* hb = ws;
    // Flags: 8 rowg x 4 octets x 16 ints (64-B line per octet) — R8/R10-proven.
    int* flags  = (int*)(ws + CTR_OFF);
    int* myflag = flags + rowg*64 + (colg >> 3)*16 + (colg & 7);
    int* pollp  = flags + rowg*64 + wave*16 + (lane & 7);

    __shared__ float red[4][32][32];   // 16 KB: cross-wave K-reduction

    // ---- one-time: register-resident B fragments, hi/lo split (proven) ----
    // B-frag layout (32x32x16): n = lane&31, k = (lane>>5)*8 + j
    bf16x8 whh_hi[16], whh_lo[16];
    {
        const int nn = c0 + ln31;
        #pragma unroll
        for (int kk = 0; kk < 16; ++kk) {
            const int kb = wave*256 + kk*16 + lhalf*8;
            #pragma unroll
            for (int j = 0; j < 8; ++j) {
                float v = Whh[(size_t)(kb + j)*HID + nn];
                __bf16 h = (__bf16)v;
                whh_hi[kk][j] = h;
                whh_lo[kk][j] = (__bf16)(v - (float)h);
            }
        }
    }
    bf16x8 whx_hi[2], whx_lo[2];
    {
        const int nn = c0 + ln31;
        #pragma unroll
        for (int kk = 0; kk < 2; ++kk) {
            const int kb = wave*32 + kk*16 + lhalf*8;
            #pragma unroll
            for (int j = 0; j < 8; ++j) {
                float v = Whx[(size_t)(kb + j)*HID + nn];
                __bf16 h = (__bf16)v;
                whx_hi[kk][j] = h;
                whx_lo[kk][j] = (__bf16)(v - (float)h);
            }
        }
    }
    // Store/epilogue assignment: thread -> (row = tid>>3, cols scq..scq+3)
    const int srow = tid >> 3;
    const int scq  = (tid & 7) * 4;
    const float4 bh4 = *(const float4*)(bh + c0 + scq);
    const size_t xrow_base = (size_t)(r0 + ln31) * (SEQ*IND) + wave*32 + lhalf*8;
    // SECTOR-SPLIT K-blocked h layout. Per (buf,rowg), per kb block of 128
    // u64s:  u64 index = kb*128 + half*64 + (k16>>3)*32 + m,  half=(k16>>2)&1.
    // Reader: lane's q[0] at kb*128 + lane (first 512 B), q[1] at
    // kb*128 + 64 + lane (second 512 B) — each load instruction covers a
    // disjoint contiguous 512-B half; every 64-B sector requested exactly once
    // (R10's interleave requested each sector twice).
    const int sc = c0 + scq;                  // this thread's 4 cols, sc%4==0
    const int soffq = (sc >> 4)*128 + ((sc >> 2) & 1)*64 + ((sc >> 3) & 1)*32 + srow;

    for (int t = 0; t < SEQ; ++t) {
        const int cur = t & 1;
        const int nxt = cur ^ 1;
        f32x16 acc0{}, acc1{};

        // ---- x(t) contribution: h-independent, overlaps flag/store latency.
        // 3-pass hi/lo split: AhiBhi + AhiBlo + AloBhi  (bit-identical to R10)
        {
            const float* xp = x + xrow_base + (size_t)t*IND;
            #pragma unroll
            for (int kk = 0; kk < 2; ++kk) {
                const float4* p = (const float4*)(xp + kk*16);
                float4 v0 = p[0], v1 = p[1];
                float vv[8] = {v0.x,v0.y,v0.z,v0.w,v1.x,v1.y,v1.z,v1.w};
                bf16x8 ahi, alo;
                #pragma unroll
                for (int j = 0; j < 8; ++j) {
                    __bf16 h = (__bf16)vv[j];
                    ahi[j] = h;
                    alo[j] = (__bf16)(vv[j] - (float)h);
                }
                acc0 = __builtin_amdgcn_mfma_f32_32x32x16_bf16(ahi, whx_hi[kk], acc0, 0,0,0);
                acc1 = __builtin_amdgcn_mfma_f32_32x32x16_bf16(ahi, whx_lo[kk], acc1, 0,0,0);
                acc0 = __builtin_amdgcn_mfma_f32_32x32x16_bf16(alo, whx_hi[kk], acc0, 0,0,0);
            }
        }

        // ---- per-wave wait for THIS wave's 8 producers, then its K-slice of
        // h(t) @ Whh. t==0: h0 == 0, skip entirely.
        if (t > 0) {
            for (;;) {
                int v = __hip_atomic_load(pollp, __ATOMIC_RELAXED, __HIP_MEMORY_SCOPE_AGENT);
                if (__all(v >= t)) break;
            }
            asm volatile("" ::: "memory");   // no compiler hoist of h loads

            // A-frags: stage ALL 32 uncached 8B loads first (one latency
            // exposure, R10-proven), then the 32 MFMAs. Sector-split address:
            // q[0] sweeps bytes [0,512) of the kb block, q[1] bytes [512,1024).
            const u64* hq = (const u64*)(hb + (size_t)(cur*NROWG + rowg)*ROWG_ELEMS);
            Pack8 pa[16];
            #pragma unroll
            for (int kk = 0; kk < 16; ++kk) {
                const int idx = (wave*16 + kk)*128 + lane;
                pa[kk].q[0] = __hip_atomic_load(hq + idx,      __ATOMIC_RELAXED, __HIP_MEMORY_SCOPE_AGENT);
                pa[kk].q[1] = __hip_atomic_load(hq + idx + 64, __ATOMIC_RELAXED, __HIP_MEMORY_SCOPE_AGENT);
            }
            __builtin_amdgcn_sched_group_barrier(0x020, 32, 0);  // 32 VMEM reads
            __builtin_amdgcn_sched_group_barrier(0x008, 32, 0);  // 32 MFMAs
            #pragma unroll
            for (int kk = 0; kk < 16; ++kk) {
                acc0 = __builtin_amdgcn_mfma_f32_32x32x16_bf16(pa[kk].v, whh_hi[kk], acc0, 0,0,0);
                acc1 = __builtin_amdgcn_mfma_f32_32x32x16_bf16(pa[kk].v, whh_lo[kk], acc1, 0,0,0);
            }
        }

        // ---- cross-wave K reduction through LDS
        // C/D layout (32x32): col=lane&31, row=(reg&3)+8*(reg>>2)+4*(lane>>5)
        #pragma unroll
        for (int r = 0; r < 16; ++r) {
            const int row = (r & 3) + 8*(r >> 2) + 4*lhalf;
            red[wave][row][ln31] = acc0[r] + acc1[r];
        }
        __syncthreads();
        {
            // thread -> (srow, cols scq..scq+3): float4 LDS reads, one 8B
            // write-through store into the sector-split K-blocked buffer.
            const float4 s0 = *(const float4*)&red[0][srow][scq];
            const float4 s1 = *(const float4*)&red[1][srow][scq];
            const float4 s2 = *(const float4*)&red[2][srow][scq];
            const float4 s3 = *(const float4*)&red[3][srow][scq];
            float z0 = s0.x + s1.x + s2.x + s3.x + bh4.x;
            float z1 = s0.y + s1.y + s2.y + s3.y + bh4.y;
            float z2 = s0.z + s1.z + s2.z + s3.z + bh4.z;
            float z3 = s0.w + s1.w + s2.w + s3.w + bh4.w;
            Pack4 pk;
            pk.h[0] = (__bf16)fast_tanh(z0);
            pk.h[1] = (__bf16)fast_tanh(z1);
            pk.h[2] = (__bf16)fast_tanh(z2);
            pk.h[3] = (__bf16)fast_tanh(z3);
            u64* hnq = (u64*)(hb + (size_t)(nxt*NROWG + rowg)*ROWG_ELEMS) + soffq;
            __hip_atomic_store(hnq, pk.q, __ATOMIC_RELAXED, __HIP_MEMORY_SCOPE_AGENT);
        }
        // __syncthreads drains vmcnt(0) per wave => every wave's sc1 store
        // reached the coherence point before tid0 publishes the arrival.
        __syncthreads();
        if (tid == 0) {
            __hip_atomic_store(myflag, t + 1, __ATOMIC_RELAXED, __HIP_MEMORY_SCOPE_AGENT);
        }
    }

    // ---- epilogue: colg==0 WG of each row-group computes o + softmax
    if (colg == 0) {
        // Need ALL 32 producers of this rowg: lanes 0..31 cover 4 octets x 8.
        int* epip = flags + rowg*64 + ((lane >> 3) & 3)*16 + (lane & 7);
        for (;;) {
            int v = __hip_atomic_load(epip, __ATOMIC_RELAXED, __HIP_MEMORY_SCOPE_AGENT);
            if (__all(v >= SEQ)) break;
        }
        asm volatile("" ::: "memory");
        __syncthreads();
        // after t=255, final h is in buffer 0 (sector-split K-blocked layout)
        const u64* hq0 = (const u64*)(hb + (size_t)(0*NROWG + rowg)*ROWG_ELEMS);
        float* obuf = &red[0][0][0];    // reuse LDS, 320 floats
        for (int idx = tid; idx < 32*OUTD; idx += 256) {
            const int row = idx / OUTD;      // m within rowg
            const int c   = idx - row*OUTD;
            float s = bo[c];
            #pragma unroll 8
            for (int k4 = 0; k4 < HID/4; ++k4) {
                const int k = k4*4;
                Pack4 p;
                p.q = __hip_atomic_load(hq0 + (k>>4)*128 + ((k>>2)&1)*64 + ((k>>3)&1)*32 + row,
                                        __ATOMIC_RELAXED, __HIP_MEMORY_SCOPE_AGENT);
                const float* wr = Why + (size_t)k*OUTD + c;
                s += (float)p.h[0]*wr[0] + (float)p.h[1]*wr[OUTD]
                   + (float)p.h[2]*wr[2*OUTD] + (float)p.h[3]*wr[3*OUTD];
            }
            obuf[idx] = s;
        }
        __syncthreads();
        if (tid < 32) {
            float m = -1e30f;
            #pragma unroll
            for (int c = 0; c < OUTD; ++c) m = fmaxf(m, obuf[tid*OUTD+c]);
            float e[OUTD]; float ssum = 0.f;
            #pragma unroll
            for (int c = 0; c < OUTD; ++c) { e[c] = __expf(obuf[tid*OUTD+c] - m); ssum += e[c]; }
            const float inv = 1.0f / ssum;
            #pragma unroll
            for (int c = 0; c < OUTD; ++c) out[(size_t)(r0+tid)*OUTD + c] = e[c]*inv;
        }
    }
}

extern "C" void kernel_launch(void* const* d_in, const int* in_sizes, int n_in,
                              void* d_out, int out_size, void* d_ws, size_t ws_size,
                              hipStream_t stream)
{
    const float* x   = (const float*)d_in[0];
    const float* Whx = (const float*)d_in[1];
    const float* Whh = (const float*)d_in[2];
    const float* bh  = (const float*)d_in[3];
    const float* Why = (const float*)d_in[4];
    const float* bo  = (const float*)d_in[5];
    float* out = (float*)d_out;
    __bf16* ws = (__bf16*)d_ws;

    // Zero the flag region: SAME offset and SAME 2 KB extent as all passing rounds.
    hipMemsetAsync((char*)d_ws + (size_t)CTR_OFF*sizeof(__bf16), 0,
                   (size_t)NROWG*64*sizeof(int), stream);

    void* args[] = { &x, &Whx, &Whh, &bh, &Why, &bo, &out, &ws };
    hipLaunchCooperativeKernel((const void*)rnn_persistent,
                               dim3(NROWG*NCOLG), dim3(256), args, 0, stream);
}

// Round 13
// 862.718 us; speedup vs baseline: 3.1619x; 1.3180x over previous
//
#include <hip/hip_runtime.h>
#include <hip/hip_bf16.h>

#define BATCH 256
#define SEQ   256
#define IND   128
#define HID   1024
#define OUTD  10

#define NCOLG 16           // 16 column groups of 64 cols
#define NROWG 16           // 16 row groups of 16 rows  => grid 256 (proven size)
#define ROWG_ELEMS (HID*16)     // one rowg h-tile: 16384 bf16 = 32 KB
#define CTR_OFF (2*BATCH*HID)   // flags after the two H buffers (proven offset)

typedef __bf16 bf16x8 __attribute__((ext_vector_type(8)));
typedef float  f32x4  __attribute__((ext_vector_type(4)));
typedef unsigned long long u64;

union Pack4 { u64 q; __bf16 h[4]; };
union Pack8 { u64 q[2]; bf16x8 v; };

__device__ __forceinline__ float fast_tanh(float z) {
    float e = __expf(-2.0f * fabsf(z));
    float t = (1.0f - e) / (1.0f + e);
    return copysignf(t, z);
}

__global__ __launch_bounds__(256, 1)
void rnn_persistent(const float* __restrict__ x,
                    const float* __restrict__ Whx,
                    const float* __restrict__ Whh,
                    const float* __restrict__ bh,
                    const float* __restrict__ Why,
                    const float* __restrict__ bo,
                    float* __restrict__ out,
                    __bf16* __restrict__ ws)
{
    const int tid  = threadIdx.x;
    const int lane = tid & 63;
    const int wave = tid >> 6;
    const int bx   = blockIdx.x;
    const int colg = bx & (NCOLG-1);
    const int rowg = bx >> 4;          // 0..15
    const int c0 = colg * 64;
    const int r0 = rowg * 16;
    const int ln15 = lane & 15;
    const int quad = lane >> 4;        // 0..3

    __bf16* hb = ws;
    // Flags: one 64-B line (16 ints) per rowg, 1 KB total (inside proven 2 KB
    // extent). Producer (rowg,colg) owns flags[rowg*16+colg]. Consumer wave w
    // needs K [256w,256w+256) = cols of colgs 4w..4w+3.
    int* flags  = (int*)(ws + CTR_OFF);
    int* myflag = flags + rowg*16 + colg;
    int* pollp  = flags + rowg*16 + wave*4 + (lane & 3);

    __shared__ float red[4][16][64];   // 16 KB: cross-wave K-reduction

    // ---- one-time: register-resident B fragments (16x16x32 layout:
    // n = lane&15, k = quad*8 + j). Whh HI-ONLY (register budget);
    // x-side keeps hi/lo.
    bf16x8 whh_hi[4][8];               // 4 col-tiles x 8 K-chunks of 32
    #pragma unroll
    for (int ct = 0; ct < 4; ++ct) {
        const int nn = c0 + ct*16 + ln15;
        #pragma unroll
        for (int c = 0; c < 8; ++c) {
            const int kb = wave*256 + c*32 + quad*8;
            #pragma unroll
            for (int j = 0; j < 8; ++j)
                whh_hi[ct][c][j] = (__bf16)Whh[(size_t)(kb + j)*HID + nn];
        }
    }
    bf16x8 whx_hi[4], whx_lo[4];
    #pragma unroll
    for (int ct = 0; ct < 4; ++ct) {
        const int nn = c0 + ct*16 + ln15;
        const int kb = wave*32 + quad*8;
        #pragma unroll
        for (int j = 0; j < 8; ++j) {
            float v = Whx[(size_t)(kb + j)*HID + nn];
            __bf16 h = (__bf16)v;
            whx_hi[ct][j] = h;
            whx_lo[ct][j] = (__bf16)(v - (float)h);
        }
    }
    // Reducer/store assignment: thread -> (row = tid>>4, cols scol..scol+3)
    const int srow = tid >> 4;          // 0..15
    const int scol = (tid & 15) * 4;    // 0..60
    const float4 bh4 = *(const float4*)(bh + c0 + scol);
    const size_t xrow_base = (size_t)(r0 + ln15) * (SEQ*IND) + wave*32 + quad*8;
    // Chunk-blocked h layout per (buf,rowg): 32 chunks (K=32 each) of 1 KB.
    //   u64 index = g*128 + (quad_k*16 + m)*2 + ((kc>>2)&1)
    // where g = k/32, kc = k%32, quad_k = kc>>3, m = row-r0. A-frag reader:
    // lane reads u64s g*128 + lane*2 + {0,1} (dense 1 KB per chunk).
    const int sc = c0 + scol;
    const int soffq = (sc >> 5)*128 + (((sc & 31) >> 3)*16 + srow)*2 + ((sc >> 2) & 1);

    for (int t = 0; t < SEQ; ++t) {
        const int cur = t & 1;
        const int nxt = cur ^ 1;
        f32x4 acc0{}, acc1{}, acc2{}, acc3{};

        // ---- x(t) contribution: h-independent, overlaps flag/store latency.
        // A-frag (16x16x32): lane (m=ln15, quad) holds k = quad*8+j.
        // 3-pass hi/lo: AhiBhi + AloBhi + AhiBlo.
        {
            const float* xp = x + xrow_base + (size_t)t*IND;
            float4 v0 = ((const float4*)xp)[0];
            float4 v1 = ((const float4*)xp)[1];
            float vv[8] = {v0.x,v0.y,v0.z,v0.w,v1.x,v1.y,v1.z,v1.w};
            bf16x8 ahi, alo;
            #pragma unroll
            for (int j = 0; j < 8; ++j) {
                __bf16 h = (__bf16)vv[j];
                ahi[j] = h;
                alo[j] = (__bf16)(vv[j] - (float)h);
            }
            acc0 = __builtin_amdgcn_mfma_f32_16x16x32_bf16(ahi, whx_hi[0], acc0, 0,0,0);
            acc0 = __builtin_amdgcn_mfma_f32_16x16x32_bf16(alo, whx_hi[0], acc0, 0,0,0);
            acc0 = __builtin_amdgcn_mfma_f32_16x16x32_bf16(ahi, whx_lo[0], acc0, 0,0,0);
            acc1 = __builtin_amdgcn_mfma_f32_16x16x32_bf16(ahi, whx_hi[1], acc1, 0,0,0);
            acc1 = __builtin_amdgcn_mfma_f32_16x16x32_bf16(alo, whx_hi[1], acc1, 0,0,0);
            acc1 = __builtin_amdgcn_mfma_f32_16x16x32_bf16(ahi, whx_lo[1], acc1, 0,0,0);
            acc2 = __builtin_amdgcn_mfma_f32_16x16x32_bf16(ahi, whx_hi[2], acc2, 0,0,0);
            acc2 = __builtin_amdgcn_mfma_f32_16x16x32_bf16(alo, whx_hi[2], acc2, 0,0,0);
            acc2 = __builtin_amdgcn_mfma_f32_16x16x32_bf16(ahi, whx_lo[2], acc2, 0,0,0);
            acc3 = __builtin_amdgcn_mfma_f32_16x16x32_bf16(ahi, whx_hi[3], acc3, 0,0,0);
            acc3 = __builtin_amdgcn_mfma_f32_16x16x32_bf16(alo, whx_hi[3], acc3, 0,0,0);
            acc3 = __builtin_amdgcn_mfma_f32_16x16x32_bf16(ahi, whx_lo[3], acc3, 0,0,0);
        }

        // ---- per-wave wait for THIS wave's 4 producers, then its K-slice of
        // h(t) @ Whh. t==0: h0 == 0, skip entirely.
        if (t > 0) {
            for (;;) {
                int v = __hip_atomic_load(pollp, __ATOMIC_RELAXED, __HIP_MEMORY_SCOPE_AGENT);
                if (__all(v >= t)) break;
            }
            asm volatile("" ::: "memory");   // no compiler hoist of h loads

            // A-frags: stage ALL 16 uncached 8B loads first (one latency
            // exposure, R10-proven), then the 32 MFMAs.
            const u64* hq = (const u64*)(hb + (size_t)(cur*NROWG + rowg)*ROWG_ELEMS);
            Pack8 pa[8];
            #pragma unroll
            for (int c = 0; c < 8; ++c) {
                const int idx = (wave*8 + c)*128 + lane*2;
                pa[c].q[0] = __hip_atomic_load(hq + idx,     __ATOMIC_RELAXED, __HIP_MEMORY_SCOPE_AGENT);
                pa[c].q[1] = __hip_atomic_load(hq + idx + 1, __ATOMIC_RELAXED, __HIP_MEMORY_SCOPE_AGENT);
            }
            __builtin_amdgcn_sched_group_barrier(0x020, 16, 0);  // 16 VMEM reads
            __builtin_amdgcn_sched_group_barrier(0x008, 32, 0);  // 32 MFMAs
            #pragma unroll
            for (int c = 0; c < 8; ++c) {
                acc0 = __builtin_amdgcn_mfma_f32_16x16x32_bf16(pa[c].v, whh_hi[0][c], acc0, 0,0,0);
                acc1 = __builtin_amdgcn_mfma_f32_16x16x32_bf16(pa[c].v, whh_hi[1][c], acc1, 0,0,0);
                acc2 = __builtin_amdgcn_mfma_f32_16x16x32_bf16(pa[c].v, whh_hi[2][c], acc2, 0,0,0);
                acc3 = __builtin_amdgcn_mfma_f32_16x16x32_bf16(pa[c].v, whh_hi[3][c], acc3, 0,0,0);
            }
        }

        // ---- cross-wave K reduction through LDS
        // C/D layout (16x16): col = lane&15, row = quad*4 + reg
        #pragma unroll
        for (int r = 0; r < 4; ++r) {
            const int row = quad*4 + r;
            red[wave][row][ln15]      = acc0[r];
            red[wave][row][16 + ln15] = acc1[r];
            red[wave][row][32 + ln15] = acc2[r];
            red[wave][row][48 + ln15] = acc3[r];
        }
        __syncthreads();
        {
            // thread -> (srow, cols scol..scol+3): float4 LDS reads, one 8B
            // write-through store into the chunk-blocked buffer.
            const float4 s0 = *(const float4*)&red[0][srow][scol];
            const float4 s1 = *(const float4*)&red[1][srow][scol];
            const float4 s2 = *(const float4*)&red[2][srow][scol];
            const float4 s3 = *(const float4*)&red[3][srow][scol];
            float z0 = s0.x + s1.x + s2.x + s3.x + bh4.x;
            float z1 = s0.y + s1.y + s2.y + s3.y + bh4.y;
            float z2 = s0.z + s1.z + s2.z + s3.z + bh4.z;
            float z3 = s0.w + s1.w + s2.w + s3.w + bh4.w;
            Pack4 pk;
            pk.h[0] = (__bf16)fast_tanh(z0);
            pk.h[1] = (__bf16)fast_tanh(z1);
            pk.h[2] = (__bf16)fast_tanh(z2);
            pk.h[3] = (__bf16)fast_tanh(z3);
            u64* hnq = (u64*)(hb + (size_t)(nxt*NROWG + rowg)*ROWG_ELEMS) + soffq;
            __hip_atomic_store(hnq, pk.q, __ATOMIC_RELAXED, __HIP_MEMORY_SCOPE_AGENT);
        }
        // __syncthreads drains vmcnt(0) per wave => every wave's sc1 store
        // reached the coherence point before tid0 publishes the arrival.
        __syncthreads();
        if (tid == 0) {
            __hip_atomic_store(myflag, t + 1, __ATOMIC_RELAXED, __HIP_MEMORY_SCOPE_AGENT);
        }
    }

    // ---- epilogue: colg==0 WG of each row-group computes o + softmax
    if (colg == 0) {
        int* epip = flags + rowg*16 + (lane & 15);  // all 16 producers
        for (;;) {
            int v = __hip_atomic_load(epip, __ATOMIC_RELAXED, __HIP_MEMORY_SCOPE_AGENT);
            if (__all(v >= SEQ)) break;
        }
        asm volatile("" ::: "memory");
        __syncthreads();
        // after t=255, final h is in buffer 0 (chunk-blocked layout)
        const u64* hq0 = (const u64*)(hb + (size_t)(0*NROWG + rowg)*ROWG_ELEMS);
        float* obuf = &red[0][0][0];    // reuse LDS, 160 floats
        for (int idx = tid; idx < 16*OUTD; idx += 256) {
            const int row = idx / OUTD;      // m within rowg (0..15)
            const int c   = idx - row*OUTD;
            float s = bo[c];
            #pragma unroll 8
            for (int k4 = 0; k4 < HID/4; ++k4) {
                const int k = k4*4;
                Pack4 p;
                p.q = __hip_atomic_load(hq0 + (k>>5)*128 + (((k&31)>>3)*16 + row)*2 + ((k>>2)&1),
                                        __ATOMIC_RELAXED, __HIP_MEMORY_SCOPE_AGENT);
                const float* wr = Why + (size_t)k*OUTD + c;
                s += (float)p.h[0]*wr[0] + (float)p.h[1]*wr[OUTD]
                   + (float)p.h[2]*wr[2*OUTD] + (float)p.h[3]*wr[3*OUTD];
            }
            obuf[idx] = s;
        }
        __syncthreads();
        if (tid < 16) {
            float m = -1e30f;
            #pragma unroll
            for (int c = 0; c < OUTD; ++c) m = fmaxf(m, obuf[tid*OUTD+c]);
            float e[OUTD]; float ssum = 0.f;
            #pragma unroll
            for (int c = 0; c < OUTD; ++c) { e[c] = __expf(obuf[tid*OUTD+c] - m); ssum += e[c]; }
            const float inv = 1.0f / ssum;
            #pragma unroll
            for (int c = 0; c < OUTD; ++c) out[(size_t)(r0+tid)*OUTD + c] = e[c]*inv;
        }
    }
}

extern "C" void kernel_launch(void* const* d_in, const int* in_sizes, int n_in,
                              void* d_out, int out_size, void* d_ws, size_t ws_size,
                              hipStream_t stream)
{
    const float* x   = (const float*)d_in[0];
    const float* Whx = (const float*)d_in[1];
    const float* Whh = (const float*)d_in[2];
    const float* bh  = (const float*)d_in[3];
    const float* Why = (const float*)d_in[4];
    const float* bo  = (const float*)d_in[5];
    float* out = (float*)d_out;
    __bf16* ws = (__bf16*)d_ws;

    // Zero the flag region: SAME offset and SAME 2 KB extent as all passing
    // rounds (flags occupy the first 1 KB of it here).
    hipMemsetAsync((char*)d_ws + (size_t)CTR_OFF*sizeof(__bf16), 0,
                   (size_t)2048, stream);

    void* args[] = { &x, &Whx, &Whh, &bh, &Why, &bo, &out, &ws };
    hipLaunchCooperativeKernel((const void*)rnn_persistent,
                               dim3(NROWG*NCOLG), dim3(256), args, 0, stream);
}